// Round 9
// baseline (62.291 us; speedup 1.0000x reference)
//
#include <hip/hip_runtime.h>
#include <hip/hip_bf16.h>

// GAT layer: out[b,i,j] = lrelu( (h@W@a1)[b,i] + (h@W@a2)[b,j] )
// B=4, N=4096, IN_F=256, OUT_F=64. Output: 4*4096*4096 fp32 = 256 MiB (write-bound).
// e1 = h@(W@a1), e2 = h@(W@a2) — Wh never materialized.
// K2 is a fill-kernel clone: zero vector-memory reads inside the store loop
// (loads and stores share vmcnt on CDNA; any in-loop load-use wait drains the
// store queue). e1 values arrive via one 64-lane gather per batch + readlane
// (bit-cast through int — the builtin is int-typed!).

#define B_DIM 4
#define N_DIM 4096
#define IN_F 256
#define OUT_F 64
#define SLOPE 0.2f

typedef float f32x4 __attribute__((ext_vector_type(4)));

// K1: fused v + dots. 1024 blocks x 256 threads (16 rows of h per block).
__global__ __launch_bounds__(256) void gat_dots(
        const float* __restrict__ h, const float* __restrict__ W,
        const float* __restrict__ a,
        float* __restrict__ e1, float* __restrict__ e2) {
    __shared__ float v1s[IN_F];
    __shared__ float v2s[IN_F];
    const int t    = threadIdx.x;
    const int lane = t & 63;
    const int wid  = t >> 6;

    // ---- phase 1: v = W @ a (coalesced, wave-cooperative) ----
    {
        const int rgrp = lane >> 4;
        const int ch   = lane & 15;
        const f32x4 a1c = reinterpret_cast<const f32x4*>(a)[ch];
        const f32x4 a2c = reinterpret_cast<const f32x4*>(a + OUT_F)[ch];
        #pragma unroll
        for (int it = 0; it < 16; ++it) {
            const int row = wid * 64 + it * 4 + rgrp;
            const f32x4 wv = *reinterpret_cast<const f32x4*>(W + row * OUT_F + ch * 4);
            float s1 = wv.x * a1c.x + wv.y * a1c.y + wv.z * a1c.z + wv.w * a1c.w;
            float s2 = wv.x * a2c.x + wv.y * a2c.y + wv.z * a2c.z + wv.w * a2c.w;
            #pragma unroll
            for (int m = 8; m >= 1; m >>= 1) {
                s1 += __shfl_xor(s1, m);
                s2 += __shfl_xor(s2, m);
            }
            if (ch == 0) { v1s[row] = s1; v2s[row] = s2; }
        }
    }
    __syncthreads();

    // ---- phase 2: wave-per-row dots (4 rows per wave) ----
    const f32x4 v1 = reinterpret_cast<const f32x4*>(v1s)[lane];
    const f32x4 v2 = reinterpret_cast<const f32x4*>(v2s)[lane];
    const int base = blockIdx.x * 16 + wid * 4;

    #pragma unroll
    for (int r = 0; r < 4; ++r) {
        const int row = base + r;
        const f32x4 hv = reinterpret_cast<const f32x4*>(h + (size_t)row * IN_F)[lane];
        float d1 = hv.x * v1.x + hv.y * v1.y + hv.z * v1.z + hv.w * v1.w;
        float d2 = hv.x * v2.x + hv.y * v2.y + hv.z * v2.z + hv.w * v2.w;
        #pragma unroll
        for (int m = 32; m >= 1; m >>= 1) {
            d1 += __shfl_xor(d1, m);
            d2 += __shfl_xor(d2, m);
        }
        if (lane == 0) { e1[row] = d1; e2[row] = d2; }
    }
}

// K2: epilogue, fill-clone. 256 blocks x 256 threads = 65536 threads.
// Block b: row0 = b>>2 (uniform), col4 = (b&3)*256 + tid (contiguous 1 KB/wave).
// Per batch: 1 e2 load (loop-invariant) + 1 gather of 64 e1 values into lane
// regs; then 64 iterations of {readlane(bitcast) + 12 VALU + 1 dwordx4 store}
// — zero vector loads in the loop, so the store queue fills to HW depth.
__global__ __launch_bounds__(256) void gat_epilogue(
        const float* __restrict__ e1, const float* __restrict__ e2,
        float* __restrict__ out) {
    const int tid  = threadIdx.x;
    const int b4   = blockIdx.x;
    const int row0 = b4 >> 2;                      // 0..63, block-uniform
    const int col4 = (b4 & 3) * 256 + tid;         // f32x4 column, 0..1023
    const int lane = tid & 63;

    for (int b = 0; b < B_DIM; ++b) {
        const float* e1b = e1 + b * N_DIM;
        // loop-invariant e2 value for this thread's column
        const f32x4 c = reinterpret_cast<const f32x4*>(e2 + b * N_DIM)[col4];
        // gather: lane l holds e1b[row0 + 64*l]; keep the raw bits in an int
        const int e1bits = __builtin_bit_cast(int, e1b[row0 + 64 * lane]);

        f32x4* outb = reinterpret_cast<f32x4*>(out + (size_t)b * N_DIM * N_DIM);

        #pragma unroll 8
        for (int it = 0; it < 64; ++it) {
            const float s = __builtin_bit_cast(float,
                                __builtin_amdgcn_readlane(e1bits, it));  // SALU broadcast
            f32x4 o;
            float ex = s + c.x; o.x = fmaxf(ex, SLOPE * ex);
            float ey = s + c.y; o.y = fmaxf(ey, SLOPE * ey);
            float ez = s + c.z; o.z = fmaxf(ez, SLOPE * ez);
            float ew = s + c.w; o.w = fmaxf(ew, SLOPE * ew);
            outb[(size_t)(row0 + 64 * it) * (N_DIM / 4) + col4] = o;
        }
    }
}

extern "C" void kernel_launch(void* const* d_in, const int* in_sizes, int n_in,
                              void* d_out, int out_size, void* d_ws, size_t ws_size,
                              hipStream_t stream) {
    const float* h = (const float*)d_in[0];   // 4*4096*256
    const float* W = (const float*)d_in[1];   // 256*64
    const float* a = (const float*)d_in[2];   // 128

    float* ws = (float*)d_ws;
    float* e1 = ws;                    // 16384 floats (indexed b*N + i)
    float* e2 = ws + 16384;            // 16384 floats (indexed b*N + j)

    gat_dots<<<1024, 256, 0, stream>>>(h, W, a, e1, e2);
    gat_epilogue<<<256, 256, 0, stream>>>(e1, e2, (float*)d_out);
}